// Round 1
// baseline (1002.624 us; speedup 1.0000x reference)
//
#include <hip/hip_runtime.h>
#include <stdint.h>

#define M_ROWS 8192
#define C_DIM  512
#define K_CODES 8192

// ws layout:
//   best   : u64[8192]  @ 0        (65536 B)
//   cnhalf : f32[8192]  @ 65536    (32768 B)
//   count  : u32[8192]  @ 98304    (32768 B)
//   lpart  : f32[2048]  @ 131072   (8192 B)   -> total 139264 B
#define WS_BEST    0
#define WS_CNHALF  65536
#define WS_COUNT   98304
#define WS_LPART   131072
#define WS_TOTAL   139264

// ---------------- Kernel A: half column norms of emb ----------------
__global__ __launch_bounds__(256) void vq_colnorm(const float* __restrict__ emb,
                                                  float* __restrict__ cnhalf) {
    int k = blockIdx.x * 256 + threadIdx.x;
    float s = 0.f;
    for (int c = 0; c < C_DIM; ++c) {
        float v = emb[c * K_CODES + k];
        s = fmaf(v, v, s);
    }
    cnhalf[k] = 0.5f * s;
}

// ---------------- Kernel B: fused score GEMM + per-row argmax ----------------
// score[m,k] = x[m]·e[:,k] - 0.5*||e_k||^2 ; argmin(dist) == argmax(score)
#define BM 64
#define BN 64
#define BC 32
#define PADW 68   // 32xPADW tiles; 16B-aligned float4 rows, bank-spread

__device__ __forceinline__ uint32_t sortable_key(float f) {
    uint32_t b = __float_as_uint(f);
    return ((int)b >= 0) ? (b | 0x80000000u) : ~b;
}

__global__ __launch_bounds__(256) void vq_score_argmax(
        const float* __restrict__ x, const float* __restrict__ emb,
        const float* __restrict__ cnhalf, unsigned long long* __restrict__ best) {
    __shared__ __align__(16) float xT[BC][PADW];  // transposed x tile: [cc][row]
    __shared__ __align__(16) float el[BC][PADW];  // emb tile: [cc][col]

    const int tid = threadIdx.x;
    const int tx = tid & 15;        // 16 col-groups
    const int ty = tid >> 4;        // 16 row-groups
    const int row0 = blockIdx.y * BM;
    const int col0 = blockIdx.x * BN;

    float acc[4][4] = {};

    for (int ct = 0; ct < C_DIM; ct += BC) {
        __syncthreads();
        // stage x chunk (64 rows x 32 cols), transposed into LDS
        #pragma unroll
        for (int h = 0; h < 2; ++h) {
            int f = tid + h * 256;           // 0..511 float4 slots
            int r  = f >> 3;                 // 0..63
            int c4 = (f & 7) * 4;            // 0..28
            const float4 v = *(const float4*)&x[(size_t)(row0 + r) * C_DIM + ct + c4];
            xT[c4 + 0][r] = v.x; xT[c4 + 1][r] = v.y;
            xT[c4 + 2][r] = v.z; xT[c4 + 3][r] = v.w;
        }
        // stage emb chunk (32 rows x 64 cols), row-major
        #pragma unroll
        for (int h = 0; h < 2; ++h) {
            int f = tid + h * 256;
            int cc = f >> 4;                 // 0..31
            int c4 = (f & 15) * 4;           // 0..60
            *(float4*)&el[cc][c4] = *(const float4*)&emb[(size_t)(ct + cc) * K_CODES + col0 + c4];
        }
        __syncthreads();

        #pragma unroll
        for (int cc = 0; cc < BC; ++cc) {
            float4 a4 = *(const float4*)&xT[cc][ty * 4];
            float4 b4 = *(const float4*)&el[cc][tx * 4];
            float av[4] = {a4.x, a4.y, a4.z, a4.w};
            float bv[4] = {b4.x, b4.y, b4.z, b4.w};
            #pragma unroll
            for (int i = 0; i < 4; ++i)
                #pragma unroll
                for (int j = 0; j < 4; ++j)
                    acc[i][j] = fmaf(av[i], bv[j], acc[i][j]);
        }
    }

    // epilogue: subtract half-norm, pack, reduce per row within block
    float4 hn4 = *(const float4*)&cnhalf[col0 + tx * 4];
    float hn[4] = {hn4.x, hn4.y, hn4.z, hn4.w};

    __syncthreads();  // done reading xT/el; reuse xT as u64 scratch
    unsigned long long* red = (unsigned long long*)&xT[0][0];  // 64*16 u64 = 8192 B

    #pragma unroll
    for (int i = 0; i < 4; ++i) {
        int row = ty * 4 + i;
        unsigned long long pk = 0ull;
        #pragma unroll
        for (int j = 0; j < 4; ++j) {
            float s = acc[i][j] - hn[j];
            uint32_t col = (uint32_t)(col0 + tx * 4 + j);
            unsigned long long p = ((unsigned long long)sortable_key(s) << 32) | (uint32_t)(~col);
            pk = (p > pk) ? p : pk;   // equal key -> larger ~col -> smaller col
        }
        red[row * 16 + tx] = pk;
    }
    __syncthreads();
    if (tid < 64) {
        unsigned long long v = red[tid * 16];
        #pragma unroll
        for (int j = 1; j < 16; ++j) {
            unsigned long long p = red[tid * 16 + j];
            v = (p > v) ? p : v;
        }
        atomicMax(&best[row0 + tid], v);
    }
}

// ---------------- Kernel C: gather codewords, quantized out, loss partials, histogram ----------------
__global__ __launch_bounds__(256) void vq_gather(
        const float* __restrict__ x, const float* __restrict__ emb,
        const unsigned long long* __restrict__ best,
        float* __restrict__ out, unsigned int* __restrict__ count,
        float* __restrict__ lpart) {
    __shared__ float ls[4];
    const int lane = threadIdx.x & 63;
    const int w = threadIdx.x >> 6;
    const int r = blockIdx.x * 4 + w;

    unsigned long long v = best[r];
    const int idx = (int)(~(unsigned int)v) & (K_CODES - 1);

    float s = 0.f;
    #pragma unroll
    for (int h = 0; h < 2; ++h) {
        int c = lane * 4 + h * 256;
        float4 xv = *(const float4*)&x[(size_t)r * C_DIM + c];
        float4 q;
        q.x = emb[(size_t)(c + 0) * K_CODES + idx];
        q.y = emb[(size_t)(c + 1) * K_CODES + idx];
        q.z = emb[(size_t)(c + 2) * K_CODES + idx];
        q.w = emb[(size_t)(c + 3) * K_CODES + idx];
        float d0 = q.x - xv.x, d1 = q.y - xv.y, d2 = q.z - xv.z, d3 = q.w - xv.w;
        s += d0 * d0 + d1 * d1 + d2 * d2 + d3 * d3;
        *(float4*)&out[(size_t)r * C_DIM + c] = q;  // quantized_st == quantized numerically
    }
    #pragma unroll
    for (int off = 32; off > 0; off >>= 1) s += __shfl_down(s, off);
    if (lane == 0) {
        ls[w] = s;
        atomicAdd(&count[idx], 1u);
    }
    __syncthreads();
    if (threadIdx.x == 0) lpart[blockIdx.x] = ls[0] + ls[1] + ls[2] + ls[3];
}

// ---------------- Kernel D: finalize loss + perplexity ----------------
__global__ __launch_bounds__(256) void vq_finalize(
        const float* __restrict__ running, const unsigned int* __restrict__ count,
        const float* __restrict__ lpart, float* __restrict__ out) {
    __shared__ float sh[256];
    const int tid = threadIdx.x;

    // loss = 1.25 * mean((q-x)^2)
    float s = 0.f;
    for (int i = tid; i < 2048; i += 256) s += lpart[i];
    sh[tid] = s; __syncthreads();
    for (int st = 128; st > 0; st >>= 1) {
        if (tid < st) sh[tid] += sh[tid + st];
        __syncthreads();
    }
    if (tid == 0) out[(size_t)M_ROWS * C_DIM] = 1.25f * sh[0] / (float)(M_ROWS * C_DIM);
    __syncthreads();

    // perplexity over new running probs
    float s2 = 0.f;
    for (int k = tid; k < K_CODES; k += 256) {
        float p = 0.9f * running[k] + 0.1f * ((float)count[k] * (1.0f / (float)M_ROWS));
        s2 += p * logf(p + 1e-10f);
    }
    sh[tid] = s2; __syncthreads();
    for (int st = 128; st > 0; st >>= 1) {
        if (tid < st) sh[tid] += sh[tid + st];
        __syncthreads();
    }
    if (tid == 0) out[(size_t)M_ROWS * C_DIM + 1] = expf(-sh[0]);
}

extern "C" void kernel_launch(void* const* d_in, const int* in_sizes, int n_in,
                              void* d_out, int out_size, void* d_ws, size_t ws_size,
                              hipStream_t stream) {
    const float* x       = (const float*)d_in[0];
    const float* emb     = (const float*)d_in[1];
    const float* running = (const float*)d_in[2];
    float* out = (float*)d_out;
    char* ws = (char*)d_ws;

    unsigned long long* best = (unsigned long long*)(ws + WS_BEST);
    float*        cnhalf = (float*)(ws + WS_CNHALF);
    unsigned int* count  = (unsigned int*)(ws + WS_COUNT);
    float*        lpart  = (float*)(ws + WS_LPART);

    hipMemsetAsync(d_ws, 0, WS_TOTAL, stream);

    vq_colnorm<<<K_CODES / 256, 256, 0, stream>>>(emb, cnhalf);
    vq_score_argmax<<<dim3(K_CODES / BN, M_ROWS / BM), 256, 0, stream>>>(x, emb, cnhalf, best);
    vq_gather<<<M_ROWS / 4, 256, 0, stream>>>(x, emb, best, out, count, lpart);
    vq_finalize<<<1, 256, 0, stream>>>(running, count, lpart, out);
}

// Round 2
// 367.096 us; speedup vs baseline: 2.7312x; 2.7312x over previous
//
#include <hip/hip_runtime.h>
#include <stdint.h>

#define M_ROWS 8192
#define C_DIM  512
#define K_CODES 8192

// ws layout:
//   best   : u64[8192]        @ 0
//   cnhalf : f32[8192]        @ 65536
//   count  : u32[8192]        @ 98304
//   lpart  : f32[2048]        @ 131072      (zeroed region ends at 139264)
//   A2     : bf16[8192][1024] @ 1048576     (X_hi | X_lo), 16 MB
//   BT     : bf16[8192][1024] @ 17825792    (E^T_hi | E^T_lo), 16 MB
#define WS_BEST    0
#define WS_CNHALF  65536
#define WS_COUNT   98304
#define WS_LPART   131072
#define WS_ZERO_SZ 139264
#define WS_A2      1048576
#define WS_BT      17825792

typedef __attribute__((ext_vector_type(8))) short short8_t;
typedef __attribute__((ext_vector_type(4))) float f32x4;

__device__ __forceinline__ short f32_to_bf16_rne(float v) {
    uint32_t u = __float_as_uint(v);
    uint32_t r = (u + 0x7FFFu + ((u >> 16) & 1u)) >> 16;
    return (short)r;
}
__device__ __forceinline__ float bf16_to_f32(short s) {
    return __uint_as_float(((uint32_t)(uint16_t)s) << 16);
}
__device__ __forceinline__ uint32_t sortable_key(float f) {
    uint32_t b = __float_as_uint(f);
    return ((int)b >= 0) ? (b | 0x80000000u) : ~b;
}

// ---------------- conv_x: x fp32 -> A2 = [X_hi | X_lo] bf16, row-major [8192][1024] ----------------
__global__ __launch_bounds__(256) void vq_conv_x(const float* __restrict__ x,
                                                 short* __restrict__ A2) {
    int idx = blockIdx.x * 256 + threadIdx.x;       // over 8192*512/4
    int m = idx >> 7;
    int c4 = (idx & 127) * 4;
    float4 v = *(const float4*)&x[(size_t)m * C_DIM + c4];
    float vv[4] = {v.x, v.y, v.z, v.w};
    short hi[4], lo[4];
    #pragma unroll
    for (int j = 0; j < 4; ++j) {
        hi[j] = f32_to_bf16_rne(vv[j]);
        lo[j] = f32_to_bf16_rne(vv[j] - bf16_to_f32(hi[j]));
    }
    *(short4*)&A2[(size_t)m * 1024 + c4]       = *(short4*)hi;
    *(short4*)&A2[(size_t)m * 1024 + 512 + c4] = *(short4*)lo;
}

// ---------------- conv_e: emb fp32 [512][8192] -> BT = [E^T_hi | E^T_lo] bf16 [8192][1024] ----------------
__global__ __launch_bounds__(256) void vq_conv_e(const float* __restrict__ emb,
                                                 short* __restrict__ BT) {
    __shared__ float t[64][65];
    const int tid = threadIdx.x;
    const int nb = blockIdx.x * 64;   // code block (128)
    const int cb = blockIdx.y * 64;   // channel block (8)
    #pragma unroll
    for (int i = 0; i < 16; ++i) {
        int c = (tid >> 6) + i * 4;
        t[c][tid & 63] = emb[(size_t)(cb + c) * K_CODES + nb + (tid & 63)];
    }
    __syncthreads();
    const int n = tid >> 2;
    const int cp = (tid & 3) * 16;
    short hibuf[16], lobuf[16];
    #pragma unroll
    for (int i = 0; i < 16; ++i) {
        float v = t[cp + i][n];
        hibuf[i] = f32_to_bf16_rne(v);
        lobuf[i] = f32_to_bf16_rne(v - bf16_to_f32(hibuf[i]));
    }
    size_t base = (size_t)(nb + n) * 1024 + cb;
    *(short8_t*)&BT[base + 0]       = *(short8_t*)&hibuf[0];
    *(short8_t*)&BT[base + 8]       = *(short8_t*)&hibuf[8];
    *(short8_t*)&BT[base + 512]     = *(short8_t*)&lobuf[0];
    *(short8_t*)&BT[base + 512 + 8] = *(short8_t*)&lobuf[8];
}

// ---------------- colnorm: 0.5*||e_k||^2 (fp32, accurate) ----------------
__global__ __launch_bounds__(256) void vq_colnorm(const float* __restrict__ emb,
                                                  float* __restrict__ cnhalf) {
    int k = blockIdx.x * 256 + threadIdx.x;
    float s = 0.f;
    for (int c = 0; c < C_DIM; ++c) {
        float v = emb[(size_t)c * K_CODES + k];
        s = fmaf(v, v, s);
    }
    cnhalf[k] = 0.5f * s;
}

// ---------------- MFMA score GEMM + fused per-row argmax ----------------
// S = A2 . BT^T over K'=1536 virtual (hh, lh, hl passes share the K loop)
__global__ __launch_bounds__(256) void vq_mfma_argmax(
        const short* __restrict__ A2, const short* __restrict__ BT,
        const float* __restrict__ cnhalf, unsigned long long* __restrict__ best) {
    __shared__ short sA[128 * 32];
    __shared__ short sB[128 * 32];

    const int tid  = threadIdx.x;
    const int lane = tid & 63;
    const int w    = tid >> 6;
    const int wr   = (w >> 1) * 64;
    const int wc   = (w & 1) * 64;
    const int l15  = lane & 15;
    const int l4   = lane >> 4;

    const int row0 = blockIdx.y * 128;
    const int col0 = blockIdx.x * 128;

    f32x4 acc[4][4] = {};

    for (int s = 0; s < 48; ++s) {
        int akt, bkt;
        if (s < 16)      { akt = s * 32;              bkt = s * 32; }
        else if (s < 32) { akt = 512 + (s - 16) * 32; bkt = (s - 16) * 32; }
        else             { akt = (s - 32) * 32;       bkt = 512 + (s - 32) * 32; }

        __syncthreads();   // previous iteration's ds_reads done before overwrite
        #pragma unroll
        for (int h = 0; h < 2; ++h) {
            int slot = h * 256 + w * 64 + lane;
            int r  = slot >> 2;
            int kc = (slot & 3) * 8;
            __builtin_amdgcn_global_load_lds(
                (const __attribute__((address_space(1))) uint32_t*)(const void*)
                    (A2 + (size_t)(row0 + r) * 1024 + akt + kc),
                (__attribute__((address_space(3))) uint32_t*)(&sA[slot * 8]),
                16, 0, 0);
            __builtin_amdgcn_global_load_lds(
                (const __attribute__((address_space(1))) uint32_t*)(const void*)
                    (BT + (size_t)(col0 + r) * 1024 + bkt + kc),
                (__attribute__((address_space(3))) uint32_t*)(&sB[slot * 8]),
                16, 0, 0);
        }
        __syncthreads();   // compiler drains vmcnt before barrier -> LDS ready

        short8_t af[4], bf[4];
        #pragma unroll
        for (int mi = 0; mi < 4; ++mi)
            af[mi] = *(const short8_t*)&sA[(wr + mi * 16 + l15) * 32 + l4 * 8];
        #pragma unroll
        for (int ni = 0; ni < 4; ++ni)
            bf[ni] = *(const short8_t*)&sB[(wc + ni * 16 + l15) * 32 + l4 * 8];

        #pragma unroll
        for (int mi = 0; mi < 4; ++mi)
            #pragma unroll
            for (int ni = 0; ni < 4; ++ni)
                acc[mi][ni] = __builtin_amdgcn_mfma_f32_16x16x32_bf16(
                    af[mi], bf[ni], acc[mi][ni], 0, 0, 0);
    }

    // epilogue: score = acc - cnhalf, pack (key|~col), reduce, atomicMax per row
    float hn[4];
    #pragma unroll
    for (int ni = 0; ni < 4; ++ni)
        hn[ni] = cnhalf[col0 + wc + ni * 16 + l15];

    #pragma unroll
    for (int mi = 0; mi < 4; ++mi) {
        #pragma unroll
        for (int reg = 0; reg < 4; ++reg) {
            unsigned long long pk = 0ull;
            #pragma unroll
            for (int ni = 0; ni < 4; ++ni) {
                float sc = acc[mi][ni][reg] - hn[ni];
                uint32_t col = (uint32_t)(col0 + wc + ni * 16 + l15);
                unsigned long long p =
                    ((unsigned long long)sortable_key(sc) << 32) | (uint32_t)(~col);
                pk = (p > pk) ? p : pk;
            }
            #pragma unroll
            for (int off = 1; off < 16; off <<= 1) {
                unsigned long long q = __shfl_xor(pk, off);
                pk = (q > pk) ? q : pk;
            }
            if (l15 == 0) {
                int row = row0 + wr + mi * 16 + l4 * 4 + reg;
                atomicMax(&best[row], pk);
            }
        }
    }
}

// ---------------- gather + loss partials + histogram ----------------
__global__ __launch_bounds__(256) void vq_gather(
        const float* __restrict__ x, const float* __restrict__ emb,
        const unsigned long long* __restrict__ best,
        float* __restrict__ out, unsigned int* __restrict__ count,
        float* __restrict__ lpart) {
    __shared__ float ls[4];
    const int lane = threadIdx.x & 63;
    const int w = threadIdx.x >> 6;
    const int r = blockIdx.x * 4 + w;

    unsigned long long v = best[r];
    const int idx = (int)(~(unsigned int)v) & (K_CODES - 1);

    float s = 0.f;
    #pragma unroll
    for (int h = 0; h < 2; ++h) {
        int c = lane * 4 + h * 256;
        float4 xv = *(const float4*)&x[(size_t)r * C_DIM + c];
        float4 q;
        q.x = emb[(size_t)(c + 0) * K_CODES + idx];
        q.y = emb[(size_t)(c + 1) * K_CODES + idx];
        q.z = emb[(size_t)(c + 2) * K_CODES + idx];
        q.w = emb[(size_t)(c + 3) * K_CODES + idx];
        float d0 = q.x - xv.x, d1 = q.y - xv.y, d2 = q.z - xv.z, d3 = q.w - xv.w;
        s += d0 * d0 + d1 * d1 + d2 * d2 + d3 * d3;
        *(float4*)&out[(size_t)r * C_DIM + c] = q;
    }
    #pragma unroll
    for (int off = 32; off > 0; off >>= 1) s += __shfl_down(s, off);
    if (lane == 0) {
        ls[w] = s;
        atomicAdd(&count[idx], 1u);
    }
    __syncthreads();
    if (threadIdx.x == 0) lpart[blockIdx.x] = ls[0] + ls[1] + ls[2] + ls[3];
}

// ---------------- finalize: loss + perplexity ----------------
__global__ __launch_bounds__(256) void vq_finalize(
        const float* __restrict__ running, const unsigned int* __restrict__ count,
        const float* __restrict__ lpart, float* __restrict__ out) {
    __shared__ float sh[256];
    const int tid = threadIdx.x;

    float s = 0.f;
    for (int i = tid; i < 2048; i += 256) s += lpart[i];
    sh[tid] = s; __syncthreads();
    for (int st = 128; st > 0; st >>= 1) {
        if (tid < st) sh[tid] += sh[tid + st];
        __syncthreads();
    }
    if (tid == 0) out[(size_t)M_ROWS * C_DIM] = 1.25f * sh[0] / (float)(M_ROWS * C_DIM);
    __syncthreads();

    float s2 = 0.f;
    for (int k = tid; k < K_CODES; k += 256) {
        float p = 0.9f * running[k] + 0.1f * ((float)count[k] * (1.0f / (float)M_ROWS));
        s2 += p * logf(p + 1e-10f);
    }
    sh[tid] = s2; __syncthreads();
    for (int st = 128; st > 0; st >>= 1) {
        if (tid < st) sh[tid] += sh[tid + st];
        __syncthreads();
    }
    if (tid == 0) out[(size_t)M_ROWS * C_DIM + 1] = expf(-sh[0]);
}

extern "C" void kernel_launch(void* const* d_in, const int* in_sizes, int n_in,
                              void* d_out, int out_size, void* d_ws, size_t ws_size,
                              hipStream_t stream) {
    const float* x       = (const float*)d_in[0];
    const float* emb     = (const float*)d_in[1];
    const float* running = (const float*)d_in[2];
    float* out = (float*)d_out;
    char* ws = (char*)d_ws;

    unsigned long long* best = (unsigned long long*)(ws + WS_BEST);
    float*        cnhalf = (float*)(ws + WS_CNHALF);
    unsigned int* count  = (unsigned int*)(ws + WS_COUNT);
    float*        lpart  = (float*)(ws + WS_LPART);
    short*        A2     = (short*)(ws + WS_A2);
    short*        BT     = (short*)(ws + WS_BT);

    hipMemsetAsync(d_ws, 0, WS_ZERO_SZ, stream);

    vq_conv_x<<<M_ROWS * C_DIM / 4 / 256, 256, 0, stream>>>(x, A2);
    vq_conv_e<<<dim3(K_CODES / 64, C_DIM / 64), 256, 0, stream>>>(emb, BT);
    vq_colnorm<<<K_CODES / 256, 256, 0, stream>>>(emb, cnhalf);
    vq_mfma_argmax<<<dim3(K_CODES / 128, M_ROWS / 128), 256, 0, stream>>>(A2, BT, cnhalf, best);
    vq_gather<<<M_ROWS / 4, 256, 0, stream>>>(x, emb, best, out, count, lpart);
    vq_finalize<<<1, 256, 0, stream>>>(running, count, lpart, out);
}

// Round 3
// 342.478 us; speedup vs baseline: 2.9276x; 1.0719x over previous
//
#include <hip/hip_runtime.h>
#include <stdint.h>

#define M_ROWS 8192
#define C_DIM  512
#define K_CODES 8192

// ws layout:
//   best   : u64[8192]        @ 0
//   cnhalf : f32[8192]        @ 65536
//   count  : u32[8192]        @ 98304
//   lpart  : f32[2048]        @ 131072      (zeroed region = 139264 B = 17408 u64)
//   A2     : bf16[8192][1024] @ 1048576     (X_hi | X_lo), 16 MB
//   BT     : bf16[8192][1024] @ 17825792    (E^T_hi | E^T_lo), 16 MB
#define WS_BEST     0
#define WS_CNHALF   65536
#define WS_COUNT    98304
#define WS_LPART    131072
#define WS_ZERO_U64 17408
#define WS_A2       1048576
#define WS_BT       17825792

typedef __attribute__((ext_vector_type(8))) short short8_t;
typedef __attribute__((ext_vector_type(4))) float f32x4;

__device__ __forceinline__ short f32_to_bf16_rne(float v) {
    uint32_t u = __float_as_uint(v);
    uint32_t r = (u + 0x7FFFu + ((u >> 16) & 1u)) >> 16;
    return (short)r;
}
__device__ __forceinline__ float bf16_to_f32(short s) {
    return __uint_as_float(((uint32_t)(uint16_t)s) << 16);
}
__device__ __forceinline__ uint32_t sortable_key(float f) {
    uint32_t b = __float_as_uint(f);
    return ((int)b >= 0) ? (b | 0x80000000u) : ~b;
}

// ---------------- conv_x: x fp32 -> A2 = [X_hi | X_lo] bf16 [8192][1024]; also zeroes ws head ----------------
__global__ __launch_bounds__(256) void vq_conv_x(const float* __restrict__ x,
                                                 short* __restrict__ A2,
                                                 unsigned long long* __restrict__ wszero) {
    int idx = blockIdx.x * 256 + threadIdx.x;       // over 8192*512/4 = 1048576
    if (idx < WS_ZERO_U64) wszero[idx] = 0ull;      // best/cnhalf/count/lpart
    int m = idx >> 7;
    int c4 = (idx & 127) * 4;
    float4 v = *(const float4*)&x[(size_t)m * C_DIM + c4];
    float vv[4] = {v.x, v.y, v.z, v.w};
    short hi[4], lo[4];
    #pragma unroll
    for (int j = 0; j < 4; ++j) {
        hi[j] = f32_to_bf16_rne(vv[j]);
        lo[j] = f32_to_bf16_rne(vv[j] - bf16_to_f32(hi[j]));
    }
    *(short4*)&A2[(size_t)m * 1024 + c4]       = *(short4*)hi;
    *(short4*)&A2[(size_t)m * 1024 + 512 + c4] = *(short4*)lo;
}

// ---------------- conv_e: emb fp32 [512][8192] -> BT = [E^T_hi | E^T_lo] bf16 [8192][1024] ----------------
__global__ __launch_bounds__(256) void vq_conv_e(const float* __restrict__ emb,
                                                 short* __restrict__ BT) {
    __shared__ float t[64][65];
    const int tid = threadIdx.x;
    const int nb = blockIdx.x * 64;   // code block
    const int cb = blockIdx.y * 64;   // channel block
    #pragma unroll
    for (int i = 0; i < 16; ++i) {
        int c = (tid >> 6) + i * 4;
        t[c][tid & 63] = emb[(size_t)(cb + c) * K_CODES + nb + (tid & 63)];
    }
    __syncthreads();
    const int n = tid >> 2;
    const int cp = (tid & 3) * 16;
    short hibuf[16], lobuf[16];
    #pragma unroll
    for (int i = 0; i < 16; ++i) {
        float v = t[cp + i][n];
        hibuf[i] = f32_to_bf16_rne(v);
        lobuf[i] = f32_to_bf16_rne(v - bf16_to_f32(hibuf[i]));
    }
    size_t base = (size_t)(nb + n) * 1024 + cb;
    *(short8_t*)&BT[base + 0]       = *(short8_t*)&hibuf[0];
    *(short8_t*)&BT[base + 8]       = *(short8_t*)&hibuf[8];
    *(short8_t*)&BT[base + 512]     = *(short8_t*)&lobuf[0];
    *(short8_t*)&BT[base + 512 + 8] = *(short8_t*)&lobuf[8];
}

// ---------------- colnorm: 0.5*||e_k||^2 (fp32, exact emb) ----------------
__global__ __launch_bounds__(256) void vq_colnorm(const float* __restrict__ emb,
                                                  float* __restrict__ cnhalf) {
    int k = blockIdx.x * 256 + threadIdx.x;
    float s = 0.f;
    for (int c = 0; c < C_DIM; ++c) {
        float v = emb[(size_t)c * K_CODES + k];
        s = fmaf(v, v, s);
    }
    cnhalf[k] = 0.5f * s;
}

// ---------------- MFMA score GEMM (256x256 tile, BK=32, 4-buf depth-3 pipeline) + argmax ----------------
// Swizzle: physical 16B-slot q = (r*4 + s) ^ (r&7)  within each [256 rows][four 16B slots] tile.
// Inverse (staging): r = ((q>>3)<<1) | (((q>>2)^(q>>4))&1); s = (q&3)^(r&3).
#define CFENCE() asm volatile("" ::: "memory")

__global__ __launch_bounds__(512, 2) void vq_mfma_argmax(
        const short* __restrict__ A2, const short* __restrict__ BT,
        const float* __restrict__ cnhalf, unsigned long long* __restrict__ best) {
    __shared__ short lds[65536];   // 4 bufs x (A[256][32] + B[256][32]) bf16 = 128 KiB

    const int tid  = threadIdx.x;
    const int lane = tid & 63;
    const int w    = tid >> 6;
    const int wr   = w >> 2;        // 0..1  (128-row half)
    const int wc   = w & 3;         // 0..3  (64-col quarter)
    const int l15  = lane & 15;
    const int l4   = lane >> 4;

    const int bid = blockIdx.x;
    const int swz = (bid & 7) * 128 + (bid >> 3);   // XCD-aware, bijective (1024 % 8 == 0)
    const int row0 = (swz >> 5) * 256;
    const int col0 = (swz & 31) * 256;

    // staging inverse-swizzle precompute (2 chunks of 512 threads each)
    const short* aSrc[2];
    const short* bSrc[2];
    #pragma unroll
    for (int c = 0; c < 2; ++c) {
        int q = c * 512 + tid;
        int r = ((q >> 3) << 1) | (((q >> 2) ^ (q >> 4)) & 1);
        int s = (q & 3) ^ (r & 3);
        aSrc[c] = A2 + (size_t)(row0 + r) * 1024 + s * 8;
        bSrc[c] = BT + (size_t)(col0 + r) * 1024 + s * 8;
    }

    // swizzled per-lane ds_read byte offsets (frag row = base + {mi,ni}*16)
    const int abase = (((wr * 128 + l15) * 64 + l4 * 16) ^ ((l15 & 7) << 4));
    const int bbase = (((wc * 64  + l15) * 64 + l4 * 16) ^ ((l15 & 7) << 4));

    f32x4 acc[8][4] = {};

    auto stage = [&](int t) {
        int akt, bkt;
        if (t < 16)      { akt = t * 32;              bkt = t * 32; }
        else if (t < 32) { akt = 512 + (t - 16) * 32; bkt = (t - 16) * 32; }
        else             { akt = (t - 32) * 32;       bkt = 512 + (t - 32) * 32; }
        short* dst = &lds[(t & 3) * 16384];
        #pragma unroll
        for (int c = 0; c < 2; ++c) {
            __builtin_amdgcn_global_load_lds(
                (const __attribute__((address_space(1))) uint32_t*)(const void*)(aSrc[c] + akt),
                (__attribute__((address_space(3))) uint32_t*)(dst + c * 4096 + tid * 8),
                16, 0, 0);
            __builtin_amdgcn_global_load_lds(
                (const __attribute__((address_space(1))) uint32_t*)(const void*)(bSrc[c] + bkt),
                (__attribute__((address_space(3))) uint32_t*)(dst + 8192 + c * 4096 + tid * 8),
                16, 0, 0);
        }
    };

    auto compute = [&](int t) {
        const char* base = (const char*)lds + (t & 3) * 32768;
        short8_t af[8], bf[4];
        #pragma unroll
        for (int mi = 0; mi < 8; ++mi)
            af[mi] = *(const short8_t*)(base + abase + mi * 1024);
        #pragma unroll
        for (int ni = 0; ni < 4; ++ni)
            bf[ni] = *(const short8_t*)(base + 16384 + bbase + ni * 1024);
        __builtin_amdgcn_s_setprio(1);
        #pragma unroll
        for (int mi = 0; mi < 8; ++mi)
            #pragma unroll
            for (int ni = 0; ni < 4; ++ni)
                acc[mi][ni] = __builtin_amdgcn_mfma_f32_16x16x32_bf16(
                    af[mi], bf[ni], acc[mi][ni], 0, 0, 0);
        __builtin_amdgcn_s_setprio(0);
    };

    stage(0); stage(1); stage(2);
    for (int t = 0; t < 45; ++t) {
        stage(t + 3);                                   // issue-before-compute (T3/T14)
        asm volatile("s_waitcnt vmcnt(12)" ::: "memory"); // tile t staged; 3 tiles in flight
        CFENCE(); __builtin_amdgcn_s_barrier(); CFENCE();
        compute(t);
        CFENCE(); __builtin_amdgcn_s_barrier(); CFENCE(); // reads done before t+4 overwrites
    }
    asm volatile("s_waitcnt vmcnt(8)" ::: "memory");
    CFENCE(); __builtin_amdgcn_s_barrier(); CFENCE();
    compute(45);
    asm volatile("s_waitcnt vmcnt(4)" ::: "memory");
    CFENCE(); __builtin_amdgcn_s_barrier(); CFENCE();
    compute(46);
    asm volatile("s_waitcnt vmcnt(0)" ::: "memory");
    CFENCE(); __builtin_amdgcn_s_barrier(); CFENCE();
    compute(47);

    // epilogue: score = acc - cnhalf, pack (key|~col), 16-lane reduce, atomicMax per row
    float hn[4];
    #pragma unroll
    for (int ni = 0; ni < 4; ++ni)
        hn[ni] = cnhalf[col0 + wc * 64 + ni * 16 + l15];

    #pragma unroll
    for (int mi = 0; mi < 8; ++mi) {
        #pragma unroll
        for (int reg = 0; reg < 4; ++reg) {
            unsigned long long pk = 0ull;
            #pragma unroll
            for (int ni = 0; ni < 4; ++ni) {
                float sc = acc[mi][ni][reg] - hn[ni];
                uint32_t col = (uint32_t)(col0 + wc * 64 + ni * 16 + l15);
                unsigned long long p =
                    ((unsigned long long)sortable_key(sc) << 32) | (uint32_t)(~col);
                pk = (p > pk) ? p : pk;
            }
            #pragma unroll
            for (int off = 1; off < 16; off <<= 1) {
                unsigned long long q = __shfl_xor(pk, off);
                pk = (q > pk) ? q : pk;
            }
            if (l15 == 0) {
                int row = row0 + wr * 128 + mi * 16 + l4 * 4 + reg;
                atomicMax(&best[row], pk);
            }
        }
    }
}

// ---------------- gather: contiguous BT row (hi+lo reconstruct), loss partials, histogram ----------------
__global__ __launch_bounds__(256) void vq_gather(
        const float* __restrict__ x, const short* __restrict__ BT,
        const unsigned long long* __restrict__ best,
        float* __restrict__ out, unsigned int* __restrict__ count,
        float* __restrict__ lpart) {
    __shared__ float ls[4];
    const int lane = threadIdx.x & 63;
    const int w = threadIdx.x >> 6;
    const int r = blockIdx.x * 4 + w;

    unsigned long long v = best[r];
    const int idx = (int)(~(unsigned int)v) & (K_CODES - 1);

    short8_t hi = *(const short8_t*)&BT[(size_t)idx * 1024 + lane * 8];
    short8_t lo = *(const short8_t*)&BT[(size_t)idx * 1024 + 512 + lane * 8];
    float q[8];
    #pragma unroll
    for (int j = 0; j < 8; ++j) q[j] = bf16_to_f32(hi[j]) + bf16_to_f32(lo[j]);

    float4 xv0 = *(const float4*)&x[(size_t)r * C_DIM + lane * 8];
    float4 xv1 = *(const float4*)&x[(size_t)r * C_DIM + lane * 8 + 4];
    float xs[8] = {xv0.x, xv0.y, xv0.z, xv0.w, xv1.x, xv1.y, xv1.z, xv1.w};
    float s = 0.f;
    #pragma unroll
    for (int j = 0; j < 8; ++j) { float d = q[j] - xs[j]; s = fmaf(d, d, s); }
    float4 o0 = {q[0], q[1], q[2], q[3]}, o1 = {q[4], q[5], q[6], q[7]};
    *(float4*)&out[(size_t)r * C_DIM + lane * 8]     = o0;
    *(float4*)&out[(size_t)r * C_DIM + lane * 8 + 4] = o1;

    #pragma unroll
    for (int off = 32; off > 0; off >>= 1) s += __shfl_down(s, off);
    if (lane == 0) { ls[w] = s; atomicAdd(&count[idx], 1u); }
    __syncthreads();
    if (threadIdx.x == 0) lpart[blockIdx.x] = ls[0] + ls[1] + ls[2] + ls[3];
}

// ---------------- finalize: loss + perplexity ----------------
__global__ __launch_bounds__(256) void vq_finalize(
        const float* __restrict__ running, const unsigned int* __restrict__ count,
        const float* __restrict__ lpart, float* __restrict__ out) {
    __shared__ float sh[256];
    const int tid = threadIdx.x;

    float s = 0.f;
    for (int i = tid; i < 2048; i += 256) s += lpart[i];
    sh[tid] = s; __syncthreads();
    for (int st = 128; st > 0; st >>= 1) {
        if (tid < st) sh[tid] += sh[tid + st];
        __syncthreads();
    }
    if (tid == 0) out[(size_t)M_ROWS * C_DIM] = 1.25f * sh[0] / (float)(M_ROWS * C_DIM);
    __syncthreads();

    float s2 = 0.f;
    for (int k = tid; k < K_CODES; k += 256) {
        float p = 0.9f * running[k] + 0.1f * ((float)count[k] * (1.0f / (float)M_ROWS));
        s2 += p * logf(p + 1e-10f);
    }
    sh[tid] = s2; __syncthreads();
    for (int st = 128; st > 0; st >>= 1) {
        if (tid < st) sh[tid] += sh[tid + st];
        __syncthreads();
    }
    if (tid == 0) out[(size_t)M_ROWS * C_DIM + 1] = expf(-sh[0]);
}

extern "C" void kernel_launch(void* const* d_in, const int* in_sizes, int n_in,
                              void* d_out, int out_size, void* d_ws, size_t ws_size,
                              hipStream_t stream) {
    const float* x       = (const float*)d_in[0];
    const float* emb     = (const float*)d_in[1];
    const float* running = (const float*)d_in[2];
    float* out = (float*)d_out;
    char* ws = (char*)d_ws;

    unsigned long long* best = (unsigned long long*)(ws + WS_BEST);
    float*        cnhalf = (float*)(ws + WS_CNHALF);
    unsigned int* count  = (unsigned int*)(ws + WS_COUNT);
    float*        lpart  = (float*)(ws + WS_LPART);
    short*        A2     = (short*)(ws + WS_A2);
    short*        BT     = (short*)(ws + WS_BT);

    vq_conv_x<<<M_ROWS * C_DIM / 4 / 256, 256, 0, stream>>>(x, A2, (unsigned long long*)ws);
    vq_conv_e<<<dim3(K_CODES / 64, C_DIM / 64), 256, 0, stream>>>(emb, BT);
    vq_colnorm<<<K_CODES / 256, 256, 0, stream>>>(emb, cnhalf);
    vq_mfma_argmax<<<(M_ROWS / 256) * (K_CODES / 256), 512, 0, stream>>>(A2, BT, cnhalf, best);
    vq_gather<<<M_ROWS / 4, 256, 0, stream>>>(x, BT, best, out, count, lpart);
    vq_finalize<<<1, 256, 0, stream>>>(running, count, lpart, out);
}

// Round 4
// 177.469 us; speedup vs baseline: 5.6496x; 1.9298x over previous
//
#include <hip/hip_runtime.h>
#include <stdint.h>

#define M_ROWS 8192
#define C_DIM  512
#define K_CODES 8192

// ws layout:
//   best   : u64[8192]       @ 0
//   cnhalf : f32[8192]       @ 65536
//   count  : u32[8192]       @ 98304
//   lpart  : f32[2048]       @ 131072     (zero region = 139264 B = 17408 u64)
//   A2     : bf16[8192][512] @ 1048576    (X_hi), 8 MB
//   BT     : bf16[8192][512] @ 9437184    (E^T_hi), 8 MB
#define WS_BEST     0
#define WS_CNHALF   65536
#define WS_COUNT    98304
#define WS_LPART    131072
#define WS_ZERO_U64 17408
#define WS_A2       1048576
#define WS_BT       9437184

typedef __attribute__((ext_vector_type(8))) short short8_t;
typedef __attribute__((ext_vector_type(4))) float f32x4;

__device__ __forceinline__ short f32_to_bf16_rne(float v) {
    uint32_t u = __float_as_uint(v);
    uint32_t r = (u + 0x7FFFu + ((u >> 16) & 1u)) >> 16;
    return (short)r;
}
__device__ __forceinline__ float bf16_to_f32(short s) {
    return __uint_as_float(((uint32_t)(uint16_t)s) << 16);
}
__device__ __forceinline__ uint32_t sortable_key(float f) {
    uint32_t b = __float_as_uint(f);
    return ((int)b >= 0) ? (b | 0x80000000u) : ~b;
}

// ---------------- conv_x: x fp32 -> A2 = X_hi bf16 [8192][512]; also zeroes ws head ----------------
__global__ __launch_bounds__(256) void vq_conv_x(const float* __restrict__ x,
                                                 short* __restrict__ A2,
                                                 unsigned long long* __restrict__ wszero) {
    int idx = blockIdx.x * 256 + threadIdx.x;       // over 8192*512/4 = 1048576
    if (idx < WS_ZERO_U64) wszero[idx] = 0ull;
    int m = idx >> 7;
    int c4 = (idx & 127) * 4;
    float4 v = *(const float4*)&x[(size_t)m * C_DIM + c4];
    short hi[4] = {f32_to_bf16_rne(v.x), f32_to_bf16_rne(v.y),
                   f32_to_bf16_rne(v.z), f32_to_bf16_rne(v.w)};
    *(short4*)&A2[(size_t)m * 512 + c4] = *(short4*)hi;
}

// ---------------- conv_e: emb fp32 [512][8192] -> BT = E^T_hi bf16 [8192][512] ----------------
__global__ __launch_bounds__(256) void vq_conv_e(const float* __restrict__ emb,
                                                 short* __restrict__ BT) {
    __shared__ float t[64][65];
    const int tid = threadIdx.x;
    const int nb = blockIdx.x * 64;   // code block
    const int cb = blockIdx.y * 64;   // channel block
    #pragma unroll
    for (int i = 0; i < 16; ++i) {
        int c = (tid >> 6) + i * 4;
        t[c][tid & 63] = emb[(size_t)(cb + c) * K_CODES + nb + (tid & 63)];
    }
    __syncthreads();
    const int n = tid >> 2;
    const int cp = (tid & 3) * 16;    // this thread's 16-channel chunk
    short hibuf[16];
    #pragma unroll
    for (int i = 0; i < 16; ++i) hibuf[i] = f32_to_bf16_rne(t[cp + i][n]);
    size_t base = (size_t)(nb + n) * 512 + cb + cp;   // (+cp: fixes R2/R3 race)
    *(short8_t*)&BT[base + 0] = *(short8_t*)&hibuf[0];
    *(short8_t*)&BT[base + 8] = *(short8_t*)&hibuf[8];
}

// ---------------- colnorm: 0.5*||e_k||^2 (fp32 exact) ----------------
__global__ __launch_bounds__(256) void vq_colnorm(const float* __restrict__ emb,
                                                  float* __restrict__ cnhalf) {
    int k = blockIdx.x * 256 + threadIdx.x;
    float s = 0.f;
    for (int c = 0; c < C_DIM; ++c) {
        float v = emb[(size_t)c * K_CODES + k];
        s = fmaf(v, v, s);
    }
    cnhalf[k] = 0.5f * s;
}

// ---------------- MFMA score GEMM (128x128 tile, BK=32, dbuf + counted vmcnt) + argmax ----------------
// LDS 16B-slot swizzle within each [128 rows][4 slots] tile: q = (row*4 + s) ^ ((row>>1)&3)
// -> 8-lane ds_read_b128 groups hit 8 distinct bank-groups. Inverse on the global source:
//    row = q>>2 ; s = (q&3) ^ ((q>>3)&3)
__global__ __launch_bounds__(256) void vq_mfma_argmax(
        const short* __restrict__ A2, const short* __restrict__ BT,
        const float* __restrict__ cnhalf, unsigned long long* __restrict__ best) {
    __shared__ short lds[16384];   // 2 bufs x (A 4096 + B 4096 shorts) = 32 KiB

    const int tid  = threadIdx.x;
    const int lane = tid & 63;
    const int w    = tid >> 6;
    const int wr   = w >> 1;        // 0..1 row half
    const int wc   = w & 1;         // 0..1 col half
    const int l15  = lane & 15;
    const int l4   = lane >> 4;

    const int row0 = blockIdx.y * 128;
    const int col0 = blockIdx.x * 128;   // gridDim.x = 64 -> col%8 pins B-panel to one XCD's L2

    // staging source pointers (inverse-swizzled), 2 slots/thread per matrix
    const short* aSrc[2];
    const short* bSrc[2];
    #pragma unroll
    for (int c = 0; c < 2; ++c) {
        int q = c * 256 + tid;
        int row = q >> 2;
        int s = (q & 3) ^ ((q >> 3) & 3);
        aSrc[c] = A2 + (size_t)(row0 + row) * 512 + s * 8;
        bSrc[c] = BT + (size_t)(col0 + row) * 512 + s * 8;
    }

    // swizzled ds_read byte offsets (frag rows differ by 16 -> +1024B, XOR term invariant)
    const int aoff = (((wr * 64 + l15) * 64 + l4 * 16)) ^ (((l15 >> 1) & 3) << 4);
    const int boff = (((wc * 64 + l15) * 64 + l4 * 16)) ^ (((l15 >> 1) & 3) << 4);

    f32x4 acc[4][4] = {};

    auto stage = [&](int t) {
        short* dst = &lds[(t & 1) * 8192];
        const int kt = t * 32;
        #pragma unroll
        for (int c = 0; c < 2; ++c) {
            int q = c * 256 + tid;
            __builtin_amdgcn_global_load_lds(
                (const __attribute__((address_space(1))) uint32_t*)(const void*)(aSrc[c] + kt),
                (__attribute__((address_space(3))) uint32_t*)(dst + q * 8), 16, 0, 0);
            __builtin_amdgcn_global_load_lds(
                (const __attribute__((address_space(1))) uint32_t*)(const void*)(bSrc[c] + kt),
                (__attribute__((address_space(3))) uint32_t*)(dst + 4096 + q * 8), 16, 0, 0);
        }
    };

    auto compute = [&](int t) {
        const char* base = (const char*)&lds[(t & 1) * 8192];
        short8_t af[4], bf[4];
        #pragma unroll
        for (int mi = 0; mi < 4; ++mi)
            af[mi] = *(const short8_t*)(base + (aoff + mi * 1024));
        #pragma unroll
        for (int ni = 0; ni < 4; ++ni)
            bf[ni] = *(const short8_t*)(base + 8192 + (boff + ni * 1024));
        #pragma unroll
        for (int mi = 0; mi < 4; ++mi)
            #pragma unroll
            for (int ni = 0; ni < 4; ++ni)
                acc[mi][ni] = __builtin_amdgcn_mfma_f32_16x16x32_bf16(
                    af[mi], bf[ni], acc[mi][ni], 0, 0, 0);
    };

    stage(0);
    #pragma unroll 1
    for (int t = 0; t < 15; ++t) {
        stage(t + 1);                                    // issue next tile first
        asm volatile("s_waitcnt vmcnt(4)" ::: "memory"); // tile t landed; t+1 in flight
        __builtin_amdgcn_s_barrier();
        compute(t);
        asm volatile("" ::: "memory");
        __builtin_amdgcn_s_barrier();                    // reads done before t+2 overwrites
    }
    asm volatile("s_waitcnt vmcnt(0)" ::: "memory");
    __builtin_amdgcn_s_barrier();
    compute(15);

    // epilogue: score = acc - cnhalf, pack (key|~col), 16-lane reduce, atomicMax per row
    float hn[4];
    #pragma unroll
    for (int ni = 0; ni < 4; ++ni)
        hn[ni] = cnhalf[col0 + wc * 64 + ni * 16 + l15];

    #pragma unroll
    for (int mi = 0; mi < 4; ++mi) {
        #pragma unroll
        for (int reg = 0; reg < 4; ++reg) {
            unsigned long long pk = 0ull;
            #pragma unroll
            for (int ni = 0; ni < 4; ++ni) {
                float sc = acc[mi][ni][reg] - hn[ni];
                uint32_t col = (uint32_t)(col0 + wc * 64 + ni * 16 + l15);
                unsigned long long p =
                    ((unsigned long long)sortable_key(sc) << 32) | (uint32_t)(~col);
                pk = (p > pk) ? p : pk;
            }
            #pragma unroll
            for (int off = 1; off < 16; off <<= 1) {
                unsigned long long q = __shfl_xor(pk, off);
                pk = (q > pk) ? q : pk;
            }
            if (l15 == 0) {
                int row = row0 + wr * 64 + mi * 16 + l4 * 4 + reg;
                atomicMax(&best[row], pk);
            }
        }
    }
}

// ---------------- gather: contiguous BT row, loss partials, histogram ----------------
__global__ __launch_bounds__(256) void vq_gather(
        const float* __restrict__ x, const short* __restrict__ BT,
        const unsigned long long* __restrict__ best,
        float* __restrict__ out, unsigned int* __restrict__ count,
        float* __restrict__ lpart) {
    __shared__ float ls[4];
    const int lane = threadIdx.x & 63;
    const int w = threadIdx.x >> 6;
    const int r = blockIdx.x * 4 + w;

    unsigned long long v = best[r];
    const int idx = (int)(~(unsigned int)v) & (K_CODES - 1);

    short8_t hi = *(const short8_t*)&BT[(size_t)idx * 512 + lane * 8];
    float q[8];
    #pragma unroll
    for (int j = 0; j < 8; ++j) q[j] = bf16_to_f32(hi[j]);

    float4 xv0 = *(const float4*)&x[(size_t)r * C_DIM + lane * 8];
    float4 xv1 = *(const float4*)&x[(size_t)r * C_DIM + lane * 8 + 4];
    float xs[8] = {xv0.x, xv0.y, xv0.z, xv0.w, xv1.x, xv1.y, xv1.z, xv1.w};
    float s = 0.f;
    #pragma unroll
    for (int j = 0; j < 8; ++j) { float d = q[j] - xs[j]; s = fmaf(d, d, s); }
    float4 o0 = {q[0], q[1], q[2], q[3]}, o1 = {q[4], q[5], q[6], q[7]};
    *(float4*)&out[(size_t)r * C_DIM + lane * 8]     = o0;
    *(float4*)&out[(size_t)r * C_DIM + lane * 8 + 4] = o1;

    #pragma unroll
    for (int off = 32; off > 0; off >>= 1) s += __shfl_down(s, off);
    if (lane == 0) { ls[w] = s; atomicAdd(&count[idx], 1u); }
    __syncthreads();
    if (threadIdx.x == 0) lpart[blockIdx.x] = ls[0] + ls[1] + ls[2] + ls[3];
}

// ---------------- finalize: loss + perplexity ----------------
__global__ __launch_bounds__(256) void vq_finalize(
        const float* __restrict__ running, const unsigned int* __restrict__ count,
        const float* __restrict__ lpart, float* __restrict__ out) {
    __shared__ float sh[256];
    const int tid = threadIdx.x;

    float s = 0.f;
    for (int i = tid; i < 2048; i += 256) s += lpart[i];
    sh[tid] = s; __syncthreads();
    for (int st = 128; st > 0; st >>= 1) {
        if (tid < st) sh[tid] += sh[tid + st];
        __syncthreads();
    }
    if (tid == 0) out[(size_t)M_ROWS * C_DIM] = 1.25f * sh[0] / (float)(M_ROWS * C_DIM);
    __syncthreads();

    float s2 = 0.f;
    for (int k = tid; k < K_CODES; k += 256) {
        float p = 0.9f * running[k] + 0.1f * ((float)count[k] * (1.0f / (float)M_ROWS));
        s2 += p * logf(p + 1e-10f);
    }
    sh[tid] = s2; __syncthreads();
    for (int st = 128; st > 0; st >>= 1) {
        if (tid < st) sh[tid] += sh[tid + st];
        __syncthreads();
    }
    if (tid == 0) out[(size_t)M_ROWS * C_DIM + 1] = expf(-sh[0]);
}

extern "C" void kernel_launch(void* const* d_in, const int* in_sizes, int n_in,
                              void* d_out, int out_size, void* d_ws, size_t ws_size,
                              hipStream_t stream) {
    const float* x       = (const float*)d_in[0];
    const float* emb     = (const float*)d_in[1];
    const float* running = (const float*)d_in[2];
    float* out = (float*)d_out;
    char* ws = (char*)d_ws;

    unsigned long long* best = (unsigned long long*)(ws + WS_BEST);
    float*        cnhalf = (float*)(ws + WS_CNHALF);
    unsigned int* count  = (unsigned int*)(ws + WS_COUNT);
    float*        lpart  = (float*)(ws + WS_LPART);
    short*        A2     = (short*)(ws + WS_A2);
    short*        BT     = (short*)(ws + WS_BT);

    vq_conv_x<<<M_ROWS * C_DIM / 4 / 256, 256, 0, stream>>>(x, A2, (unsigned long long*)ws);
    vq_conv_e<<<dim3(K_CODES / 64, C_DIM / 64), 256, 0, stream>>>(emb, BT);
    vq_colnorm<<<K_CODES / 256, 256, 0, stream>>>(emb, cnhalf);
    vq_mfma_argmax<<<dim3(K_CODES / 128, M_ROWS / 128), 256, 0, stream>>>(A2, BT, cnhalf, best);
    vq_gather<<<M_ROWS / 4, 256, 0, stream>>>(x, BT, best, out, count, lpart);
    vq_finalize<<<1, 256, 0, stream>>>(running, count, lpart, out);
}

// Round 5
// 160.824 us; speedup vs baseline: 6.2343x; 1.1035x over previous
//
#include <hip/hip_runtime.h>
#include <stdint.h>

#define M_ROWS 8192
#define C_DIM  512
#define K_CODES 8192

// ws layout:
//   best   : u64[8192]       @ 0
//   cnhalf : f32[8192]       @ 65536
//   count  : u32[8192]       @ 98304
//   lpart  : f32[2048]       @ 131072     (zero region = 139264 B = 17408 u64)
//   A2     : bf16[8192][512] @ 1048576    (X_hi), 8 MB
//   BT     : bf16[8192][512] @ 9437184    (E^T_hi), 8 MB
#define WS_BEST     0
#define WS_CNHALF   65536
#define WS_COUNT    98304
#define WS_LPART    131072
#define WS_ZERO_U64 17408
#define WS_A2       1048576
#define WS_BT       9437184

typedef __attribute__((ext_vector_type(8))) short short8_t;
typedef __attribute__((ext_vector_type(4))) float f32x4;

__device__ __forceinline__ short f32_to_bf16_rne(float v) {
    uint32_t u = __float_as_uint(v);
    uint32_t r = (u + 0x7FFFu + ((u >> 16) & 1u)) >> 16;
    return (short)r;
}
__device__ __forceinline__ float bf16_to_f32(short s) {
    return __uint_as_float(((uint32_t)(uint16_t)s) << 16);
}
__device__ __forceinline__ uint32_t sortable_key(float f) {
    uint32_t b = __float_as_uint(f);
    return ((int)b >= 0) ? (b | 0x80000000u) : ~b;
}

// ---------------- prep: fused conv_x (+ws zero) | conv_e | colnorm ----------------
__global__ __launch_bounds__(256) void vq_prep(const float* __restrict__ x,
                                               const float* __restrict__ emb,
                                               short* __restrict__ A2,
                                               short* __restrict__ BT,
                                               float* __restrict__ cnhalf,
                                               unsigned long long* __restrict__ wszero) {
    __shared__ float t[64][65];
    const int bid = blockIdx.x;
    const int tid = threadIdx.x;
    if (bid < 4096) {
        // conv_x: x fp32 -> A2 = X_hi bf16 [8192][512]; also zero ws head
        int idx = bid * 256 + tid;
        if (idx < WS_ZERO_U64) wszero[idx] = 0ull;
        int m = idx >> 7;
        int c4 = (idx & 127) * 4;
        float4 v = *(const float4*)&x[(size_t)m * C_DIM + c4];
        short hi[4] = {f32_to_bf16_rne(v.x), f32_to_bf16_rne(v.y),
                       f32_to_bf16_rne(v.z), f32_to_bf16_rne(v.w)};
        *(short4*)&A2[(size_t)m * 512 + c4] = *(short4*)hi;
    } else if (bid < 5120) {
        // conv_e: emb fp32 [512][8192] -> BT = E^T_hi bf16 [8192][512]
        int r = bid - 4096;
        int nb = (r & 127) * 64;
        int cb = (r >> 7) * 64;
        #pragma unroll
        for (int i = 0; i < 16; ++i) {
            int c = (tid >> 6) + i * 4;
            t[c][tid & 63] = emb[(size_t)(cb + c) * K_CODES + nb + (tid & 63)];
        }
        __syncthreads();
        const int n = tid >> 2;
        const int cp = (tid & 3) * 16;
        short hibuf[16];
        #pragma unroll
        for (int i = 0; i < 16; ++i) hibuf[i] = f32_to_bf16_rne(t[cp + i][n]);
        size_t base = (size_t)(nb + n) * 512 + cb + cp;
        *(short8_t*)&BT[base + 0] = *(short8_t*)&hibuf[0];
        *(short8_t*)&BT[base + 8] = *(short8_t*)&hibuf[8];
    } else {
        // colnorm: 0.5*||e_k||^2 fp32 exact
        int k = (bid - 5120) * 256 + tid;
        float s = 0.f;
        for (int c = 0; c < C_DIM; ++c) {
            float v = emb[(size_t)c * K_CODES + k];
            s = fmaf(v, v, s);
        }
        cnhalf[k] = 0.5f * s;
    }
}

// ---------------- MFMA score GEMM: 128 rows x 512 cols per block (4 col-tiles),
// BK=32, 4-buf depth-2 pipeline, ONE barrier/K-step, fused running argmax ----------------
// LDS 16B-slot swizzle (R4-verified, 0 conflicts): q = (row*4+s) ^ ((row>>1)&3);
// inverse on global source: row = q>>2, s = (q&3)^((q>>3)&3).
#define WAITV8() asm volatile("s_waitcnt vmcnt(8)" ::: "memory")
#define WAITV4() asm volatile("s_waitcnt vmcnt(4)" ::: "memory")
#define WAITV0() asm volatile("s_waitcnt vmcnt(0)" ::: "memory")

__global__ __launch_bounds__(256, 2) void vq_mfma_argmax(
        const short* __restrict__ A2, const short* __restrict__ BT,
        const float* __restrict__ cnhalf, unsigned long long* __restrict__ best) {
    __shared__ short lds[32768];   // 4 bufs x (A 4096 | B 4096 shorts) = 64 KiB

    const int tid  = threadIdx.x;
    const int lane = tid & 63;
    const int w    = tid >> 6;
    const int wr   = w >> 1;        // row half
    const int wc   = w & 1;         // col half
    const int l15  = lane & 15;
    const int l4   = lane >> 4;

    const int row0  = blockIdx.x * 128;   // x fastest: row-blocks sweep within a col-group
    const int colg0 = blockIdx.y * 512;

    // staging source pointers (inverse-swizzled)
    const short* aSrc[2];
    const short* bSrc[2];
    #pragma unroll
    for (int c = 0; c < 2; ++c) {
        int q = c * 256 + tid;
        int row = q >> 2;
        int s = (q & 3) ^ ((q >> 3) & 3);
        aSrc[c] = A2 + (size_t)(row0 + row) * 512 + s * 8;
        bSrc[c] = BT + (size_t)(colg0 + row) * 512 + s * 8;
    }

    // swizzled ds_read byte offsets
    const int aoff = (((wr * 64 + l15) * 64 + l4 * 16)) ^ (((l15 >> 1) & 3) << 4);
    const int boff = (((wc * 64 + l15) * 64 + l4 * 16)) ^ (((l15 >> 1) & 3) << 4);

    // preload all half-norms (before any staging: these retire first, keep vmcnt ladder clean)
    float hn[4][4];
    #pragma unroll
    for (int ct = 0; ct < 4; ++ct)
        #pragma unroll
        for (int ni = 0; ni < 4; ++ni)
            hn[ct][ni] = cnhalf[colg0 + ct * 128 + wc * 64 + ni * 16 + l15];

    float    rs[4][4];
    uint32_t rc[4][4];
    #pragma unroll
    for (int mi = 0; mi < 4; ++mi)
        #pragma unroll
        for (int reg = 0; reg < 4; ++reg) { rs[mi][reg] = -__builtin_inff(); rc[mi][reg] = 0u; }

    auto stage = [&](int ctile, int kk) {
        short* dst = &lds[(kk & 3) * 8192];
        const int ao = kk * 32;
        const int bo = ctile * 65536 + kk * 32;   // 128*512 shorts per col-tile
        #pragma unroll
        for (int c = 0; c < 2; ++c) {
            int q = c * 256 + tid;
            __builtin_amdgcn_global_load_lds(
                (const __attribute__((address_space(1))) uint32_t*)(const void*)(aSrc[c] + ao),
                (__attribute__((address_space(3))) uint32_t*)(dst + q * 8), 16, 0, 0);
            __builtin_amdgcn_global_load_lds(
                (const __attribute__((address_space(1))) uint32_t*)(const void*)(bSrc[c] + bo),
                (__attribute__((address_space(3))) uint32_t*)(dst + 4096 + q * 8), 16, 0, 0);
        }
    };

    f32x4 acc[4][4];

    auto compute = [&](int kk) {
        const char* base = (const char*)lds + (kk & 3) * 16384;
        short8_t af[4], bf[4];
        #pragma unroll
        for (int mi = 0; mi < 4; ++mi)
            af[mi] = *(const short8_t*)(base + (aoff + mi * 1024));
        #pragma unroll
        for (int ni = 0; ni < 4; ++ni)
            bf[ni] = *(const short8_t*)(base + 8192 + (boff + ni * 1024));
        __builtin_amdgcn_s_setprio(1);
        #pragma unroll
        for (int mi = 0; mi < 4; ++mi)
            #pragma unroll
            for (int ni = 0; ni < 4; ++ni)
                acc[mi][ni] = __builtin_amdgcn_mfma_f32_16x16x32_bf16(
                    af[mi], bf[ni], acc[mi][ni], 0, 0, 0);
        __builtin_amdgcn_s_setprio(0);
    };

    stage(0, 0); stage(0, 1);

    #pragma unroll
    for (int ct = 0; ct < 4; ++ct) {
        #pragma unroll
        for (int mi = 0; mi < 4; ++mi)
            #pragma unroll
            for (int ni = 0; ni < 4; ++ni)
                acc[mi][ni] = (f32x4){0.f, 0.f, 0.f, 0.f};

        #pragma unroll 1
        for (int k = 0; k < 14; ++k) {
            stage(ct, k + 2);
            WAITV8();
            __builtin_amdgcn_s_barrier();
            compute(k);
        }
        // k = 14
        if (ct < 3) { stage(ct + 1, 0); WAITV8(); } else { WAITV4(); }
        __builtin_amdgcn_s_barrier();
        compute(14);
        // k = 15
        if (ct < 3) { stage(ct + 1, 1); WAITV8(); } else { WAITV0(); }
        __builtin_amdgcn_s_barrier();
        compute(15);

        // fold this col-tile into the running per-lane argmax (f32 + u32, no u64 ops)
        #pragma unroll
        for (int mi = 0; mi < 4; ++mi)
            #pragma unroll
            for (int reg = 0; reg < 4; ++reg)
                #pragma unroll
                for (int ni = 0; ni < 4; ++ni) {
                    float sc = acc[mi][ni][reg] - hn[ct][ni];
                    uint32_t col = (uint32_t)(colg0 + ct * 128 + wc * 64 + ni * 16 + l15);
                    if (sc > rs[mi][reg]) { rs[mi][reg] = sc; rc[mi][reg] = col; }
                }
    }

    // final pack + 16-lane reduce + one atomicMax per (row, col-group)
    #pragma unroll
    for (int mi = 0; mi < 4; ++mi) {
        #pragma unroll
        for (int reg = 0; reg < 4; ++reg) {
            unsigned long long p =
                ((unsigned long long)sortable_key(rs[mi][reg]) << 32) |
                (uint32_t)(~rc[mi][reg]);
            #pragma unroll
            for (int off = 1; off < 16; off <<= 1) {
                unsigned long long q = __shfl_xor(p, off);
                p = (q > p) ? q : p;
            }
            if (l15 == 0) {
                int row = row0 + wr * 64 + mi * 16 + l4 * 4 + reg;
                atomicMax(&best[row], p);
            }
        }
    }
}

// ---------------- gather: contiguous BT row, loss partials, histogram ----------------
__global__ __launch_bounds__(256) void vq_gather(
        const float* __restrict__ x, const short* __restrict__ BT,
        const unsigned long long* __restrict__ best,
        float* __restrict__ out, unsigned int* __restrict__ count,
        float* __restrict__ lpart) {
    __shared__ float ls[4];
    const int lane = threadIdx.x & 63;
    const int w = threadIdx.x >> 6;
    const int r = blockIdx.x * 4 + w;

    unsigned long long v = best[r];
    const int idx = (int)(~(unsigned int)v) & (K_CODES - 1);

    short8_t hi = *(const short8_t*)&BT[(size_t)idx * 512 + lane * 8];
    float q[8];
    #pragma unroll
    for (int j = 0; j < 8; ++j) q[j] = bf16_to_f32(hi[j]);

    float4 xv0 = *(const float4*)&x[(size_t)r * C_DIM + lane * 8];
    float4 xv1 = *(const float4*)&x[(size_t)r * C_DIM + lane * 8 + 4];
    float xs[8] = {xv0.x, xv0.y, xv0.z, xv0.w, xv1.x, xv1.y, xv1.z, xv1.w};
    float s = 0.f;
    #pragma unroll
    for (int j = 0; j < 8; ++j) { float d = q[j] - xs[j]; s = fmaf(d, d, s); }
    float4 o0 = {q[0], q[1], q[2], q[3]}, o1 = {q[4], q[5], q[6], q[7]};
    *(float4*)&out[(size_t)r * C_DIM + lane * 8]     = o0;
    *(float4*)&out[(size_t)r * C_DIM + lane * 8 + 4] = o1;

    #pragma unroll
    for (int off = 32; off > 0; off >>= 1) s += __shfl_down(s, off);
    if (lane == 0) { ls[w] = s; atomicAdd(&count[idx], 1u); }
    __syncthreads();
    if (threadIdx.x == 0) lpart[blockIdx.x] = ls[0] + ls[1] + ls[2] + ls[3];
}

// ---------------- finalize: loss + perplexity ----------------
__global__ __launch_bounds__(256) void vq_finalize(
        const float* __restrict__ running, const unsigned int* __restrict__ count,
        const float* __restrict__ lpart, float* __restrict__ out) {
    __shared__ float sh[256];
    const int tid = threadIdx.x;

    float s = 0.f;
    for (int i = tid; i < 2048; i += 256) s += lpart[i];
    sh[tid] = s; __syncthreads();
    for (int st = 128; st > 0; st >>= 1) {
        if (tid < st) sh[tid] += sh[tid + st];
        __syncthreads();
    }
    if (tid == 0) out[(size_t)M_ROWS * C_DIM] = 1.25f * sh[0] / (float)(M_ROWS * C_DIM);
    __syncthreads();

    float s2 = 0.f;
    for (int k = tid; k < K_CODES; k += 256) {
        float p = 0.9f * running[k] + 0.1f * ((float)count[k] * (1.0f / (float)M_ROWS));
        s2 += p * logf(p + 1e-10f);
    }
    sh[tid] = s2; __syncthreads();
    for (int st = 128; st > 0; st >>= 1) {
        if (tid < st) sh[tid] += sh[tid + st];
        __syncthreads();
    }
    if (tid == 0) out[(size_t)M_ROWS * C_DIM + 1] = expf(-sh[0]);
}

extern "C" void kernel_launch(void* const* d_in, const int* in_sizes, int n_in,
                              void* d_out, int out_size, void* d_ws, size_t ws_size,
                              hipStream_t stream) {
    const float* x       = (const float*)d_in[0];
    const float* emb     = (const float*)d_in[1];
    const float* running = (const float*)d_in[2];
    float* out = (float*)d_out;
    char* ws = (char*)d_ws;

    unsigned long long* best = (unsigned long long*)(ws + WS_BEST);
    float*        cnhalf = (float*)(ws + WS_CNHALF);
    unsigned int* count  = (unsigned int*)(ws + WS_COUNT);
    float*        lpart  = (float*)(ws + WS_LPART);
    short*        A2     = (short*)(ws + WS_A2);
    short*        BT     = (short*)(ws + WS_BT);

    vq_prep<<<5152, 256, 0, stream>>>(x, emb, A2, BT, cnhalf, (unsigned long long*)ws);
    vq_mfma_argmax<<<dim3(M_ROWS / 128, K_CODES / 512), 256, 0, stream>>>(A2, BT, cnhalf, best);
    vq_gather<<<M_ROWS / 4, 256, 0, stream>>>(x, BT, best, out, count, lpart);
    vq_finalize<<<1, 256, 0, stream>>>(running, count, lpart, out);
}

// Round 6
// 156.337 us; speedup vs baseline: 6.4132x; 1.0287x over previous
//
#include <hip/hip_runtime.h>
#include <stdint.h>

#define M_ROWS 8192
#define C_DIM  512
#define K_CODES 8192

// ws layout:
//   best   : u64[8192]       @ 0
//   cnhalf : f32[8192]       @ 65536
//   count  : u32[8192]       @ 98304
//   lpart  : f32[2048]       @ 131072     (zero region = 139264 B = 17408 u64)
//   A2     : bf16[8192][512] @ 1048576    (X_hi), 8 MB
//   BT     : bf16[8192][512] @ 9437184    (E^T_hi), 8 MB
#define WS_BEST     0
#define WS_CNHALF   65536
#define WS_COUNT    98304
#define WS_LPART    131072
#define WS_ZERO_U64 17408
#define WS_A2       1048576
#define WS_BT       9437184

typedef __attribute__((ext_vector_type(8))) short short8_t;
typedef __attribute__((ext_vector_type(4))) float f32x4;

__device__ __forceinline__ short f32_to_bf16_rne(float v) {
    uint32_t u = __float_as_uint(v);
    uint32_t r = (u + 0x7FFFu + ((u >> 16) & 1u)) >> 16;
    return (short)r;
}
__device__ __forceinline__ float bf16_to_f32(short s) {
    return __uint_as_float(((uint32_t)(uint16_t)s) << 16);
}
__device__ __forceinline__ uint32_t sortable_key(float f) {
    uint32_t b = __float_as_uint(f);
    return ((int)b >= 0) ? (b | 0x80000000u) : ~b;
}

// ---------------- prep: fused conv_x (+ws zero) | conv_e | colnorm ----------------
__global__ __launch_bounds__(256) void vq_prep(const float* __restrict__ x,
                                               const float* __restrict__ emb,
                                               short* __restrict__ A2,
                                               short* __restrict__ BT,
                                               float* __restrict__ cnhalf,
                                               unsigned long long* __restrict__ wszero) {
    __shared__ float t[64][65];
    const int bid = blockIdx.x;
    const int tid = threadIdx.x;
    if (bid < 4096) {
        int idx = bid * 256 + tid;
        if (idx < WS_ZERO_U64) wszero[idx] = 0ull;
        int m = idx >> 7;
        int c4 = (idx & 127) * 4;
        float4 v = *(const float4*)&x[(size_t)m * C_DIM + c4];
        short hi[4] = {f32_to_bf16_rne(v.x), f32_to_bf16_rne(v.y),
                       f32_to_bf16_rne(v.z), f32_to_bf16_rne(v.w)};
        *(short4*)&A2[(size_t)m * 512 + c4] = *(short4*)hi;
    } else if (bid < 5120) {
        int r = bid - 4096;
        int nb = (r & 127) * 64;
        int cb = (r >> 7) * 64;
        #pragma unroll
        for (int i = 0; i < 16; ++i) {
            int c = (tid >> 6) + i * 4;
            t[c][tid & 63] = emb[(size_t)(cb + c) * K_CODES + nb + (tid & 63)];
        }
        __syncthreads();
        const int n = tid >> 2;
        const int cp = (tid & 3) * 16;
        short hibuf[16];
        #pragma unroll
        for (int i = 0; i < 16; ++i) hibuf[i] = f32_to_bf16_rne(t[cp + i][n]);
        size_t base = (size_t)(nb + n) * 512 + cb + cp;
        *(short8_t*)&BT[base + 0] = *(short8_t*)&hibuf[0];
        *(short8_t*)&BT[base + 8] = *(short8_t*)&hibuf[8];
    } else {
        int k = (bid - 5120) * 256 + tid;
        float s = 0.f;
        for (int c = 0; c < C_DIM; ++c) {
            float v = emb[(size_t)c * K_CODES + k];
            s = fmaf(v, v, s);
        }
        cnhalf[k] = 0.5f * s;
    }
}

// ---------------- MFMA score GEMM: 256x1024 per block (4 col-tiles of 256),
// 8 waves (2x4), per-wave 128x64, BK=32, ring-4 LDS, single barrier + counted vmcnt.
// LDS 16B-slot swizzle (R4/R5-verified, 0 conflicts): q = (row*4+s) ^ ((row>>1)&3);
// inverse on global source: row = q>>2, s = (q&3)^((q>>3)&3).
#define WAITV8() asm volatile("s_waitcnt vmcnt(8)" ::: "memory")
#define WAITV4() asm volatile("s_waitcnt vmcnt(4)" ::: "memory")
#define WAITV0() asm volatile("s_waitcnt vmcnt(0)" ::: "memory")

__global__ __launch_bounds__(512, 2) void vq_mfma_argmax(
        const short* __restrict__ A2, const short* __restrict__ BT,
        const float* __restrict__ cnhalf, unsigned long long* __restrict__ best) {
    __shared__ short lds[65536];   // 4 bufs x (A[256][32] | B[256][32]) = 128 KiB

    const int tid  = threadIdx.x;
    const int lane = tid & 63;
    const int w    = tid >> 6;
    const int wr   = w >> 2;        // 0..1: 128-row half
    const int wc   = w & 3;         // 0..3: 64-col quarter
    const int l15  = lane & 15;
    const int l4   = lane >> 4;

    const int colg0 = blockIdx.x * 1024;  // 8 col-groups: blk%8 pins B-panel (1MB) to one XCD L2
    const int row0  = blockIdx.y * 256;

    // staging source pointers (inverse-swizzled)
    const short* aSrc[2];
    const short* bSrc[2];
    #pragma unroll
    for (int c = 0; c < 2; ++c) {
        int q = c * 512 + tid;
        int row = q >> 2;
        int s = (q & 3) ^ ((q >> 3) & 3);
        aSrc[c] = A2 + (size_t)(row0 + row) * 512 + s * 8;
        bSrc[c] = BT + (size_t)(colg0 + row) * 512 + s * 8;
    }

    // swizzled ds_read byte offsets (row-deltas of 16 are multiples of 8 -> XOR term invariant)
    const int aoff = (((wr * 128 + l15) * 64 + l4 * 16)) ^ (((l15 >> 1) & 3) << 4);
    const int boff = (((wc * 64 + l15) * 64 + l4 * 16)) ^ (((l15 >> 1) & 3) << 4);

    // preload all half-norms, retire them before staging starts (clean vmcnt ladder)
    float hn[4][4];
    #pragma unroll
    for (int ct = 0; ct < 4; ++ct)
        #pragma unroll
        for (int ni = 0; ni < 4; ++ni)
            hn[ct][ni] = cnhalf[colg0 + ct * 256 + wc * 64 + ni * 16 + l15];
    WAITV0();

    auto stage = [&](int ctile, int kk) {
        short* dst = &lds[(kk & 3) * 16384];
        const int ao = kk * 32;
        const int bo = ctile * 131072 + kk * 32;   // 256 rows * 512 shorts per col-tile
        #pragma unroll
        for (int c = 0; c < 2; ++c) {
            int q = c * 512 + tid;
            __builtin_amdgcn_global_load_lds(
                (const __attribute__((address_space(1))) uint32_t*)(const void*)(aSrc[c] + ao),
                (__attribute__((address_space(3))) uint32_t*)(dst + q * 8), 16, 0, 0);
            __builtin_amdgcn_global_load_lds(
                (const __attribute__((address_space(1))) uint32_t*)(const void*)(bSrc[c] + bo),
                (__attribute__((address_space(3))) uint32_t*)(dst + 8192 + q * 8), 16, 0, 0);
        }
    };

    f32x4 acc[8][4];

    auto compute = [&](int kk) {
        const char* base = (const char*)lds + (kk & 3) * 32768;
        short8_t af[8], bf[4];
        #pragma unroll
        for (int mi = 0; mi < 8; ++mi)
            af[mi] = *(const short8_t*)(base + (aoff + mi * 1024));
        #pragma unroll
        for (int ni = 0; ni < 4; ++ni)
            bf[ni] = *(const short8_t*)(base + 16384 + (boff + ni * 1024));
        __builtin_amdgcn_s_setprio(1);
        #pragma unroll
        for (int mi = 0; mi < 8; ++mi)
            #pragma unroll
            for (int ni = 0; ni < 4; ++ni)
                acc[mi][ni] = __builtin_amdgcn_mfma_f32_16x16x32_bf16(
                    af[mi], bf[ni], acc[mi][ni], 0, 0, 0);
        __builtin_amdgcn_s_setprio(0);
    };

    stage(0, 0); stage(0, 1);

    #pragma unroll
    for (int ct = 0; ct < 4; ++ct) {
        #pragma unroll
        for (int mi = 0; mi < 8; ++mi)
            #pragma unroll
            for (int ni = 0; ni < 4; ++ni)
                acc[mi][ni] = (f32x4){0.f, 0.f, 0.f, 0.f};

        #pragma unroll 1
        for (int k = 0; k < 14; ++k) {
            stage(ct, k + 2);
            WAITV8();
            __builtin_amdgcn_s_barrier();
            compute(k);
        }
        // k = 14 (stage slot (14+2)&3 == 0 == next tile's k=0: ring stays aligned, 16 % 4 == 0)
        if (ct < 3) { stage(ct + 1, 0); WAITV8(); } else { WAITV4(); }
        __builtin_amdgcn_s_barrier();
        compute(14);
        // k = 15
        if (ct < 3) { stage(ct + 1, 1); WAITV8(); } else { WAITV0(); }
        __builtin_amdgcn_s_barrier();
        compute(15);

        // per-col-tile argmax epilogue: pack (key|~col), 16-lane reduce, atomicMax.
        // The atomics enter the vmcnt ladder AFTER stage(ct+1,0/1); in-order retirement
        // means later WAITV8s still guarantee the staged batches have landed.
        #pragma unroll
        for (int mi = 0; mi < 8; ++mi) {
            #pragma unroll
            for (int reg = 0; reg < 4; ++reg) {
                unsigned long long pk = 0ull;
                #pragma unroll
                for (int ni = 0; ni < 4; ++ni) {
                    float sc = acc[mi][ni][reg] - hn[ct][ni];
                    uint32_t col = (uint32_t)(colg0 + ct * 256 + wc * 64 + ni * 16 + l15);
                    unsigned long long p =
                        ((unsigned long long)sortable_key(sc) << 32) | (uint32_t)(~col);
                    pk = (p > pk) ? p : pk;
                }
                #pragma unroll
                for (int off = 1; off < 16; off <<= 1) {
                    unsigned long long q = __shfl_xor(pk, off);
                    pk = (q > pk) ? q : pk;
                }
                if (l15 == 0) {
                    int row = row0 + wr * 128 + mi * 16 + l4 * 4 + reg;
                    atomicMax(&best[row], pk);
                }
            }
        }
    }
}

// ---------------- gather: contiguous BT row, loss partials, histogram ----------------
__global__ __launch_bounds__(256) void vq_gather(
        const float* __restrict__ x, const short* __restrict__ BT,
        const unsigned long long* __restrict__ best,
        float* __restrict__ out, unsigned int* __restrict__ count,
        float* __restrict__ lpart) {
    __shared__ float ls[4];
    const int lane = threadIdx.x & 63;
    const int w = threadIdx.x >> 6;
    const int r = blockIdx.x * 4 + w;

    unsigned long long v = best[r];
    const int idx = (int)(~(unsigned int)v) & (K_CODES - 1);

    short8_t hi = *(const short8_t*)&BT[(size_t)idx * 512 + lane * 8];
    float q[8];
    #pragma unroll
    for (int j = 0; j < 8; ++j) q[j] = bf16_to_f32(hi[j]);

    float4 xv0 = *(const float4*)&x[(size_t)r * C_DIM + lane * 8];
    float4 xv1 = *(const float4*)&x[(size_t)r * C_DIM + lane * 8 + 4];
    float xs[8] = {xv0.x, xv0.y, xv0.z, xv0.w, xv1.x, xv1.y, xv1.z, xv1.w};
    float s = 0.f;
    #pragma unroll
    for (int j = 0; j < 8; ++j) { float d = q[j] - xs[j]; s = fmaf(d, d, s); }
    float4 o0 = {q[0], q[1], q[2], q[3]}, o1 = {q[4], q[5], q[6], q[7]};
    *(float4*)&out[(size_t)r * C_DIM + lane * 8]     = o0;
    *(float4*)&out[(size_t)r * C_DIM + lane * 8 + 4] = o1;

    #pragma unroll
    for (int off = 32; off > 0; off >>= 1) s += __shfl_down(s, off);
    if (lane == 0) { ls[w] = s; atomicAdd(&count[idx], 1u); }
    __syncthreads();
    if (threadIdx.x == 0) lpart[blockIdx.x] = ls[0] + ls[1] + ls[2] + ls[3];
}

// ---------------- finalize: loss + perplexity ----------------
__global__ __launch_bounds__(256) void vq_finalize(
        const float* __restrict__ running, const unsigned int* __restrict__ count,
        const float* __restrict__ lpart, float* __restrict__ out) {
    __shared__ float sh[256];
    const int tid = threadIdx.x;

    float s = 0.f;
    for (int i = tid; i < 2048; i += 256) s += lpart[i];
    sh[tid] = s; __syncthreads();
    for (int st = 128; st > 0; st >>= 1) {
        if (tid < st) sh[tid] += sh[tid + st];
        __syncthreads();
    }
    if (tid == 0) out[(size_t)M_ROWS * C_DIM] = 1.25f * sh[0] / (float)(M_ROWS * C_DIM);
    __syncthreads();

    float s2 = 0.f;
    for (int k = tid; k < K_CODES; k += 256) {
        float p = 0.9f * running[k] + 0.1f * ((float)count[k] * (1.0f / (float)M_ROWS));
        s2 += p * logf(p + 1e-10f);
    }
    sh[tid] = s2; __syncthreads();
    for (int st = 128; st > 0; st >>= 1) {
        if (tid < st) sh[tid] += sh[tid + st];
        __syncthreads();
    }
    if (tid == 0) out[(size_t)M_ROWS * C_DIM + 1] = expf(-sh[0]);
}

extern "C" void kernel_launch(void* const* d_in, const int* in_sizes, int n_in,
                              void* d_out, int out_size, void* d_ws, size_t ws_size,
                              hipStream_t stream) {
    const float* x       = (const float*)d_in[0];
    const float* emb     = (const float*)d_in[1];
    const float* running = (const float*)d_in[2];
    float* out = (float*)d_out;
    char* ws = (char*)d_ws;

    unsigned long long* best = (unsigned long long*)(ws + WS_BEST);
    float*        cnhalf = (float*)(ws + WS_CNHALF);
    unsigned int* count  = (unsigned int*)(ws + WS_COUNT);
    float*        lpart  = (float*)(ws + WS_LPART);
    short*        A2     = (short*)(ws + WS_A2);
    short*        BT     = (short*)(ws + WS_BT);

    vq_prep<<<5152, 256, 0, stream>>>(x, emb, A2, BT, cnhalf, (unsigned long long*)ws);
    vq_mfma_argmax<<<dim3(K_CODES / 1024, M_ROWS / 256), 512, 0, stream>>>(A2, BT, cnhalf, best);
    vq_gather<<<M_ROWS / 4, 256, 0, stream>>>(x, BT, best, out, count, lpart);
    vq_finalize<<<1, 256, 0, stream>>>(running, count, lpart, out);
}